// Round 2
// baseline (1870.272 us; speedup 1.0000x reference)
//
#include <hip/hip_runtime.h>
#include <hip/hip_bf16.h>

typedef unsigned short u16;
typedef unsigned int u32;

// Problem constants
#define CCH  64      // channels
#define HH   512
#define WWD  512
#define WS_  8
#define NWIN 16384   // 4 * 64 * 64 windows

// ---- fp32 <-> bf16 helpers (fp32 I/O, bf16 LDS staging, fp32 accum) ----
__device__ __forceinline__ float bflo(u32 p) {   // low  u16 of packed pair -> f32
    union { u32 u; float f; } v; v.u = p << 16; return v.f;
}
__device__ __forceinline__ float bfhi(u32 p) {   // high u16 of packed pair -> f32
    union { u32 u; float f; } v; v.u = p & 0xffff0000u; return v.f;
}
__device__ __forceinline__ u16 f2bf(float f) {   // round-to-nearest-even (finite)
    union { float f; u32 u; } v; v.f = f;
    u32 r = v.u + 0x7fffu + ((v.u >> 16) & 1u);
    return (u16)(r >> 16);
}
__device__ __forceinline__ u32 pack2(float a, float b) {
    return (u32)f2bf(a) | ((u32)f2bf(b) << 16);
}

// One block per 8x8 window. 256 threads = 64 tokens x 4 output-groups.
// LDS: w(bf16) 32KB + bias 1KB + x(f32) 16KB + QKV(bf16) 24KB = 73KB -> 2 blocks/CU.
__global__ __launch_bounds__(256, 2) void wmsa_kernel(
    const float* __restrict__ x,
    const float* __restrict__ wq, const float* __restrict__ bq,
    const float* __restrict__ wk, const float* __restrict__ bk,
    const float* __restrict__ wv, const float* __restrict__ bv,
    const float* __restrict__ wp, const float* __restrict__ bp,
    float* __restrict__ y)
{
    __shared__ __align__(16) u16   s_w[4 * 4096];   // [mat(q,k,v,p)][o][c] bf16
    __shared__ float               s_b[4 * 64];
    __shared__ __align__(16) float s_xf[4096];      // stage1: x [c][t]; stage3: attn out [c][t]
    __shared__ __align__(16) u16   s_qkv[3 * 4096]; // flat per window: idx = t*64+o (== h*1024+s*16+d)

    const int tid = threadIdx.x;
    const int win = blockIdx.x;
    const int b   = win >> 12;
    const int wh  = (win >> 6) & 63;
    const int wwi = win & 63;

    // ---- stage weights fp32 -> bf16 LDS ----
    {
        const float* wsrc[4] = { wq, wk, wv, wp };
        #pragma unroll
        for (int m = 0; m < 4; ++m) {
            const float4* src = (const float4*)wsrc[m];
            #pragma unroll
            for (int k = 0; k < 4; ++k) {
                int idx = k * 256 + tid;            // 1024 float4 per matrix
                float4 v = src[idx];
                *(uint2*)&s_w[m * 4096 + idx * 4] =
                    make_uint2(pack2(v.x, v.y), pack2(v.z, v.w));
            }
        }
        const float* bsrc[4] = { bq, bk, bv, bp };
        s_b[tid] = bsrc[tid >> 6][tid & 63];
    }

    // ---- stage x window (fp32): s_xf[c][t], t = i*8+j ----
    #pragma unroll
    for (int it = 0; it < 2; ++it) {
        int e = it * 256 + tid;                     // 512 rows of 8 floats
        int c = e >> 3;
        int i = e & 7;
        const float4* src = (const float4*)(x +
            ((((size_t)b * CCH + c) * HH + wh * WS_ + i) * WWD + wwi * WS_));
        float4 v0 = src[0], v1 = src[1];
        *(float4*)&s_xf[c * 64 + i * 8]     = v0;
        *(float4*)&s_xf[c * 64 + i * 8 + 4] = v1;
    }
    __syncthreads();

    const int t  = tid & 63;    // token (also attention row s)
    const int og = tid >> 6;    // output group (also attention head h) - wave-uniform

    // ---- QKV projections: Q[t][o] = sum_c x[t][c] * w[o][c] + b[o] ----
    {
        float xr[64];
        #pragma unroll
        for (int c = 0; c < 64; ++c) xr[c] = s_xf[c * 64 + t];  // stride-1 lanes: conflict-free

        for (int m = 0; m < 3; ++m) {
            for (int oi = 0; oi < 16; ++oi) {
                int o = og * 16 + oi;
                const u16* wrow = &s_w[m * 4096 + o * 64];      // wave-uniform -> broadcast
                float a0 = 0.f, a1 = 0.f, a2 = 0.f, a3 = 0.f;
                #pragma unroll
                for (int c = 0; c < 64; c += 8) {
                    uint4 P = *(const uint4*)&wrow[c];          // 8 bf16 per ds_read_b128
                    a0 += xr[c]     * bflo(P.x);
                    a1 += xr[c + 1] * bfhi(P.x);
                    a2 += xr[c + 2] * bflo(P.y);
                    a3 += xr[c + 3] * bfhi(P.y);
                    a0 += xr[c + 4] * bflo(P.z);
                    a1 += xr[c + 5] * bfhi(P.z);
                    a2 += xr[c + 6] * bflo(P.w);
                    a3 += xr[c + 7] * bfhi(P.w);
                }
                float acc = (a0 + a1) + (a2 + a3) + s_b[m * 64 + o];
                s_qkv[m * 4096 + t * 64 + o] = f2bf(acc);
            }
        }
    }
    __syncthreads();

    // ---- attention: head h = og, row s = t ----
    // Qh[s][d] = qkv_flat[h*1024 + s*16 + d]  (reference's non-standard reshape)
    {
        float qrow[16];
        {
            const u16* qb = &s_qkv[0 * 4096 + og * 1024 + t * 16];
            uint4 q0 = *(const uint4*)qb;
            uint4 q1 = *(const uint4*)(qb + 8);
            qrow[0] = bflo(q0.x); qrow[1] = bfhi(q0.x); qrow[2] = bflo(q0.y); qrow[3] = bfhi(q0.y);
            qrow[4] = bflo(q0.z); qrow[5] = bfhi(q0.z); qrow[6] = bflo(q0.w); qrow[7] = bfhi(q0.w);
            qrow[8] = bflo(q1.x); qrow[9] = bfhi(q1.x); qrow[10]= bflo(q1.y); qrow[11]= bfhi(q1.y);
            qrow[12]= bflo(q1.z); qrow[13]= bfhi(q1.z); qrow[14]= bflo(q1.w); qrow[15]= bfhi(q1.w);
        }

        float row[64];
        const u16* kbase = &s_qkv[1 * 4096 + og * 1024];   // wave-uniform base -> broadcast reads
        #pragma unroll 4
        for (int s2 = 0; s2 < 64; ++s2) {
            uint4 k0 = *(const uint4*)&kbase[s2 * 16];
            uint4 k1 = *(const uint4*)&kbase[s2 * 16 + 8];
            float a0 = qrow[0] * bflo(k0.x) + qrow[4] * bflo(k0.z);
            float a1 = qrow[1] * bfhi(k0.x) + qrow[5] * bfhi(k0.z);
            float a2 = qrow[2] * bflo(k0.y) + qrow[6] * bflo(k0.w);
            float a3 = qrow[3] * bfhi(k0.y) + qrow[7] * bfhi(k0.w);
            a0 += qrow[8]  * bflo(k1.x) + qrow[12] * bflo(k1.z);
            a1 += qrow[9]  * bfhi(k1.x) + qrow[13] * bfhi(k1.z);
            a2 += qrow[10] * bflo(k1.y) + qrow[14] * bflo(k1.w);
            a3 += qrow[11] * bfhi(k1.y) + qrow[15] * bfhi(k1.w);
            row[s2] = (a0 + a1) + (a2 + a3);
        }

        float mx = row[0];
        #pragma unroll
        for (int s2 = 1; s2 < 64; ++s2) mx = fmaxf(mx, row[s2]);
        const float ksc = 0.25f * 1.44269504088896341f;    // 1/sqrt(16) * log2(e)
        float sum = 0.f;
        #pragma unroll
        for (int s2 = 0; s2 < 64; ++s2) {
            float e = exp2f((row[s2] - mx) * ksc);
            row[s2] = e; sum += e;
        }
        const float inv = 1.0f / sum;

        float outd[16];
        #pragma unroll
        for (int d = 0; d < 16; ++d) outd[d] = 0.f;
        const u16* vbase = &s_qkv[2 * 4096 + og * 1024];
        #pragma unroll 4
        for (int s2 = 0; s2 < 64; ++s2) {
            float p = row[s2];
            uint4 v0 = *(const uint4*)&vbase[s2 * 16];
            uint4 v1 = *(const uint4*)&vbase[s2 * 16 + 8];
            outd[0]  += p * bflo(v0.x); outd[1]  += p * bfhi(v0.x);
            outd[2]  += p * bflo(v0.y); outd[3]  += p * bfhi(v0.y);
            outd[4]  += p * bflo(v0.z); outd[5]  += p * bfhi(v0.z);
            outd[6]  += p * bflo(v0.w); outd[7]  += p * bfhi(v0.w);
            outd[8]  += p * bflo(v1.x); outd[9]  += p * bfhi(v1.x);
            outd[10] += p * bflo(v1.y); outd[11] += p * bfhi(v1.y);
            outd[12] += p * bflo(v1.z); outd[13] += p * bfhi(v1.z);
            outd[14] += p * bflo(v1.w); outd[15] += p * bfhi(v1.w);
        }

        // flat f = tid*16+d -> token t' = tid/4, channel c' = (tid%4)*16+d
        const int tp    = tid >> 2;
        const int cbase = (tid & 3) * 16;
        #pragma unroll
        for (int d = 0; d < 16; ++d) {
            s_xf[(cbase + d) * 64 + tp] = outd[d] * inv;
        }
    }
    __syncthreads();

    // ---- output projection + scatter to [B,C,H,W] (fp32) ----
    {
        float orr[64];
        #pragma unroll
        for (int c = 0; c < 64; ++c) orr[c] = s_xf[c * 64 + t];

        const int i = t >> 3, j = t & 7;
        for (int oi = 0; oi < 16; ++oi) {
            int o = og * 16 + oi;
            const u16* wrow = &s_w[3 * 4096 + o * 64];
            float a0 = 0.f, a1 = 0.f, a2 = 0.f, a3 = 0.f;
            #pragma unroll
            for (int c = 0; c < 64; c += 8) {
                uint4 P = *(const uint4*)&wrow[c];
                a0 += orr[c]     * bflo(P.x);
                a1 += orr[c + 1] * bfhi(P.x);
                a2 += orr[c + 2] * bflo(P.y);
                a3 += orr[c + 3] * bfhi(P.y);
                a0 += orr[c + 4] * bflo(P.z);
                a1 += orr[c + 5] * bfhi(P.z);
                a2 += orr[c + 6] * bflo(P.w);
                a3 += orr[c + 7] * bfhi(P.w);
            }
            float acc = (a0 + a1) + (a2 + a3) + s_b[3 * 64 + o];
            size_t addr = (((size_t)b * CCH + o) * HH + wh * WS_ + i) * WWD + wwi * WS_ + j;
            y[addr] = acc;
        }
    }
}

extern "C" void kernel_launch(void* const* d_in, const int* in_sizes, int n_in,
                              void* d_out, int out_size, void* d_ws, size_t ws_size,
                              hipStream_t stream) {
    const float* x  = (const float*)d_in[0];
    const float* wq = (const float*)d_in[1];
    const float* bq = (const float*)d_in[2];
    const float* wk = (const float*)d_in[3];
    const float* bk = (const float*)d_in[4];
    const float* wv = (const float*)d_in[5];
    const float* bv = (const float*)d_in[6];
    const float* wp = (const float*)d_in[7];
    const float* bp = (const float*)d_in[8];
    float* y = (float*)d_out;

    hipLaunchKernelGGL(wmsa_kernel, dim3(NWIN), dim3(256), 0, stream,
                       x, wq, bq, wk, bk, wv, bv, wp, bp, y);
}